// Round 7
// baseline (486.856 us; speedup 1.0000x reference)
//
#include <hip/hip_runtime.h>

// CoordinateDescent, 5-dispatch pipeline. B=4, M=N=4096, R=16, fp32.
//  K1 gram1: b1 partials (v^T v)
//  K2 xv+gs: a1 = x@v (LDS vT stage, butterfly) + Gauss-Seidel u -> u_new
//  K3 gram2: b2 partials (u_new^T u_new)
//  K4 xtu:   a2 partials = x^T @ u_new, wide-n blocks for DRAM row locality
//  K5 cd_v:  reduce partials + Gauss-Seidel v -> v_new
constexpr int B = 4, M = 4096, N = 4096, R = 16;
constexpr float EPS = 1e-8f;
constexpr int GCH = 64;       // gram chunks
constexpr int NK = 256;       // n per LDS v-tile in K2
constexpr int ACH = 64;       // m-chunks in K4 (64 rows each)
constexpr int MCH = M / ACH;  // 64
constexpr int NSPAN = 1024;   // n-span per K4 block (4 KB per x-row visit)

// ---- K1/K3: b = w^T w partials: part[b][c][t], t = r2*16 + r1 ----
__global__ void gram_partial(const float* __restrict__ w, float* __restrict__ part, int L) {
  const int b = blockIdx.y, c = blockIdx.x, t = threadIdx.x;
  const int r1 = t & 15, r2 = t >> 4;
  const float* wb = w + (size_t)b * L * R;
  const int n0 = c * (L / GCH);
  float s = 0.f;
#pragma unroll 4
  for (int n = n0; n < n0 + L / GCH; ++n)
    s = fmaf(wb[(size_t)n * R + r1], wb[(size_t)n * R + r2], s);
  part[((b * GCH + c) << 8) + t] = s;
}

// ---- K2: a1 = x@v (vT in LDS) + in-block GS for this block's 16 u rows ----
__launch_bounds__(256, 4)
__global__ void xv_gs_kernel(const float* __restrict__ x, const float* __restrict__ v,
                             const float* __restrict__ u, const float* __restrict__ b1p,
                             float* __restrict__ u_new) {
  __shared__ float vT[16][NK + 1];
  __shared__ float a1s[16][17];
  __shared__ float bm[256];
  const int b = blockIdx.y, mb = blockIdx.x;
  const int t = threadIdx.x;
  const int wave = t >> 6, lane = t & 63;

  // reduce b1 partials (written by K1 dispatch) into LDS
  {
    float g = 0.f;
#pragma unroll 4
    for (int c = 0; c < GCH; ++c) g += b1p[((b * GCH + c) << 8) + t];
    bm[t] = g;
  }

  const int m0 = mb * 16 + wave * 4;
  const float* xb = x + ((size_t)b * M + m0) * N;
  const float* vb = v + (size_t)b * N * R;

  float acc[4][16];
#pragma unroll
  for (int i = 0; i < 4; ++i)
#pragma unroll
    for (int r = 0; r < 16; ++r) acc[i][r] = 0.f;

  for (int k = 0; k < N / NK; ++k) {
    const int nb = k * NK;
    __syncthreads();  // prior tile reads (and bm write at k=0) complete
#pragma unroll
    for (int q = 0; q < 4; ++q) {
      const int f = t + 256 * q;
      const int row = f >> 2;
      const int e = (f & 3) * 4;
      const float4 val = *(const float4*)(vb + (size_t)(nb + row) * R + e);
      vT[e + 0][row] = val.x;
      vT[e + 1][row] = val.y;
      vT[e + 2][row] = val.z;
      vT[e + 3][row] = val.w;
    }
    __syncthreads();

    const int nl = lane * 4;
    float4 xr[4];
#pragma unroll
    for (int mi = 0; mi < 4; ++mi)
      xr[mi] = *(const float4*)(xb + (size_t)mi * N + nb + nl);
#pragma unroll
    for (int r = 0; r < 16; ++r) {
      const float4 vv = *(const float4*)&vT[r][nl];
#pragma unroll
      for (int mi = 0; mi < 4; ++mi) {
        acc[mi][r] = fmaf(xr[mi].x, vv.x, acc[mi][r]);
        acc[mi][r] = fmaf(xr[mi].y, vv.y, acc[mi][r]);
        acc[mi][r] = fmaf(xr[mi].z, vv.z, acc[mi][r]);
        acc[mi][r] = fmaf(xr[mi].w, vv.w, acc[mi][r]);
      }
    }
  }

#pragma unroll
  for (int mi = 0; mi < 4; ++mi)
#pragma unroll
    for (int r = 0; r < 16; ++r) {
      float s = acc[mi][r];
      s += __shfl_xor(s, 1);
      s += __shfl_xor(s, 2);
      s += __shfl_xor(s, 4);
      s += __shfl_xor(s, 8);
      s += __shfl_xor(s, 16);
      s += __shfl_xor(s, 32);
      acc[mi][r] = s;
    }
  if (lane == 0) {
#pragma unroll
    for (int mi = 0; mi < 4; ++mi)
#pragma unroll
      for (int r = 0; r < 16; ++r) a1s[wave * 4 + mi][r] = acc[mi][r];
  }
  __syncthreads();

  // Gauss-Seidel for rows mb*16 .. mb*16+15 (threads 0..15, one row each)
  if (t < 16) {
    const int row = mb * 16 + t;
    const float* wp = u + ((size_t)b * M + row) * R;
    float ur[16];
#pragma unroll
    for (int rr = 0; rr < 4; ++rr) {
      const float4 wv = *(const float4*)(wp + rr * 4);
      ur[rr * 4 + 0] = wv.x; ur[rr * 4 + 1] = wv.y;
      ur[rr * 4 + 2] = wv.z; ur[rr * 4 + 3] = wv.w;
    }
#pragma unroll
    for (int r = 0; r < 16; ++r) {
      float cross = 0.f;
#pragma unroll
      for (int s = 0; s < 16; ++s)
        if (s != r) cross = fmaf(ur[s], bm[s * 16 + r], cross);
      ur[r] = (a1s[t][r] - cross + EPS) / (bm[r * 16 + r] + EPS);
    }
    float* op = u_new + ((size_t)b * M + row) * R;
    *(float4*)(op + 0)  = make_float4(ur[0],  ur[1],  ur[2],  ur[3]);
    *(float4*)(op + 4)  = make_float4(ur[4],  ur[5],  ur[6],  ur[7]);
    *(float4*)(op + 8)  = make_float4(ur[8],  ur[9],  ur[10], ur[11]);
    *(float4*)(op + 12) = make_float4(ur[12], ur[13], ur[14], ur[15]);
  }
}

// ---- K4: a2 partials, wide-n blocks. part[mc][b][n][r] over 64-row m-chunks.
// Each thread owns 4 consecutive n (float4 x loads); per-block x-row visit is
// 4 KB contiguous (DRAM-row friendly); mc reversed for L3 tail reuse of x.
__launch_bounds__(256, 4)
__global__ void xtu_partial(const float* __restrict__ x, const float* __restrict__ u,
                            float* __restrict__ part) {
  __shared__ float4 us4[MCH * 4];  // 64 rows x 16 floats = 4 KB
  const int strip = blockIdx.x;              // 4 strips of NSPAN
  const int mc = (ACH - 1) - blockIdx.y;     // reversed m-chunk order
  const int b = blockIdx.z;
  const int t = threadIdx.x;
  const int n = strip * NSPAN + t * 4;
  const float* xb = x + (size_t)b * M * N + n;
  const int mstart = mc * MCH;
  const float4* ub4 = (const float4*)(u + (size_t)b * M * R) + (size_t)mstart * 4;

  us4[t] = ub4[t];  // 256 float4 = 64 rows
  __syncthreads();

  float acc[4][16];
#pragma unroll
  for (int i = 0; i < 4; ++i)
#pragma unroll
    for (int r = 0; r < 16; ++r) acc[i][r] = 0.f;

#pragma unroll 2
  for (int ml = 0; ml < MCH; ++ml) {
    const float4 xs = *(const float4*)(xb + (size_t)(mstart + ml) * N);
    const float xv[4] = {xs.x, xs.y, xs.z, xs.w};
#pragma unroll
    for (int rr = 0; rr < 4; ++rr) {
      const float4 uv = us4[ml * 4 + rr];
#pragma unroll
      for (int i = 0; i < 4; ++i) {
        acc[i][rr * 4 + 0] = fmaf(xv[i], uv.x, acc[i][rr * 4 + 0]);
        acc[i][rr * 4 + 1] = fmaf(xv[i], uv.y, acc[i][rr * 4 + 1]);
        acc[i][rr * 4 + 2] = fmaf(xv[i], uv.z, acc[i][rr * 4 + 2]);
        acc[i][rr * 4 + 3] = fmaf(xv[i], uv.w, acc[i][rr * 4 + 3]);
      }
    }
  }

#pragma unroll
  for (int i = 0; i < 4; ++i) {
    float* p = part + (((size_t)mc * B + b) * N + (n + i)) * R;
    *(float4*)(p + 0)  = make_float4(acc[i][0],  acc[i][1],  acc[i][2],  acc[i][3]);
    *(float4*)(p + 4)  = make_float4(acc[i][4],  acc[i][5],  acc[i][6],  acc[i][7]);
    *(float4*)(p + 8)  = make_float4(acc[i][8],  acc[i][9],  acc[i][10], acc[i][11]);
    *(float4*)(p + 12) = make_float4(acc[i][12], acc[i][13], acc[i][14], acc[i][15]);
  }
}

// ---- K5: reduce a2/b2 partials + Gauss-Seidel v -> v_new ----
__global__ void cd_update_v(const float* __restrict__ a2p, const float* __restrict__ b2p,
                            const float* __restrict__ v, float* __restrict__ v_new) {
  __shared__ float bm[256];
  const int b = blockIdx.y, t = threadIdx.x;
  float g = 0.f;
#pragma unroll 4
  for (int c = 0; c < GCH; ++c) g += b2p[((b * GCH + c) << 8) + t];
  bm[t] = g;
  __syncthreads();

  const int row = blockIdx.x * 256 + t;
  const size_t stride = (size_t)B * N * R;
  const float* ap = a2p + ((size_t)b * N + row) * R;

  float a[16];
#pragma unroll
  for (int r = 0; r < 16; ++r) a[r] = 0.f;
  for (int mc = 0; mc < ACH; ++mc) {
#pragma unroll
    for (int rr = 0; rr < 4; ++rr) {
      const float4 av = *(const float4*)(ap + (size_t)mc * stride + rr * 4);
      a[rr * 4 + 0] += av.x; a[rr * 4 + 1] += av.y;
      a[rr * 4 + 2] += av.z; a[rr * 4 + 3] += av.w;
    }
  }

  const float* wp = v + ((size_t)b * N + row) * R;
  float ur[16];
#pragma unroll
  for (int rr = 0; rr < 4; ++rr) {
    const float4 wv = *(const float4*)(wp + rr * 4);
    ur[rr * 4 + 0] = wv.x; ur[rr * 4 + 1] = wv.y;
    ur[rr * 4 + 2] = wv.z; ur[rr * 4 + 3] = wv.w;
  }
#pragma unroll
  for (int r = 0; r < 16; ++r) {
    float cross = 0.f;
#pragma unroll
    for (int s = 0; s < 16; ++s)
      if (s != r) cross = fmaf(ur[s], bm[s * 16 + r], cross);
    ur[r] = (a[r] - cross + EPS) / (bm[r * 16 + r] + EPS);
  }
  float* op = v_new + ((size_t)b * N + row) * R;
  *(float4*)(op + 0)  = make_float4(ur[0],  ur[1],  ur[2],  ur[3]);
  *(float4*)(op + 4)  = make_float4(ur[4],  ur[5],  ur[6],  ur[7]);
  *(float4*)(op + 8)  = make_float4(ur[8],  ur[9],  ur[10], ur[11]);
  *(float4*)(op + 12) = make_float4(ur[12], ur[13], ur[14], ur[15]);
}

extern "C" void kernel_launch(void* const* d_in, const int* in_sizes, int n_in,
                              void* d_out, int out_size, void* d_ws, size_t ws_size,
                              hipStream_t stream) {
  (void)in_sizes; (void)n_in; (void)out_size; (void)ws_size;
  const float* x = (const float*)d_in[0];
  const float* u = (const float*)d_in[1];
  const float* v = (const float*)d_in[2];
  float* u_new = (float*)d_out;                       // B*M*R
  float* v_new = (float*)d_out + (size_t)B * M * R;   // B*N*R

  float* ws  = (float*)d_ws;
  float* b1p = ws;                                    // B*GCH*256 =   65536 f
  float* b2p = b1p + (size_t)B * GCH * 256;           //               65536 f
  float* a2p = b2p + (size_t)B * GCH * 256;           // ACH*B*N*R = 16777216 f (64 MB)

  hipLaunchKernelGGL(gram_partial, dim3(GCH, B), dim3(256), 0, stream, v, b1p, N);
  hipLaunchKernelGGL(xv_gs_kernel, dim3(M / 16, B), dim3(256), 0, stream,
                     x, v, u, b1p, u_new);
  hipLaunchKernelGGL(gram_partial, dim3(GCH, B), dim3(256), 0, stream, u_new, b2p, M);
  hipLaunchKernelGGL(xtu_partial, dim3(N / NSPAN, ACH, B), dim3(256), 0, stream,
                     x, u_new, a2p);
  hipLaunchKernelGGL(cd_update_v, dim3(N / 256, B), dim3(256), 0, stream,
                     a2p, b2p, v, v_new);
}